// Round 3
// baseline (154.155 us; speedup 1.0000x reference)
//
#include <hip/hip_runtime.h>
#include <hip/hip_fp16.h>

#define N_NODES 8192
#define F_IN    512
#define F_OUT   256
#define LOG2E   1.4426950408889634f

typedef __attribute__((ext_vector_type(8))) _Float16 half8;
typedef __attribute__((ext_vector_type(2))) __fp16   fp16x2;
typedef __attribute__((ext_vector_type(4))) float    f32x4;
typedef __attribute__((ext_vector_type(4))) int      i32x4;

union H8U4 { half8 h; uint4 u; };
union H2U  { fp16x2 h; unsigned u; };

#define AS1 __attribute__((address_space(1)))
#define AS3 __attribute__((address_space(3)))

// global->LDS direct DMA, 16B per lane, wave-uniform LDS base + lane*16.
static __device__ __forceinline__ void glds16(const uint4* g, uint4* l) {
  __builtin_amdgcn_global_load_lds((const AS1 void*)g, (AS3 void*)l, 16, 0, 0);
}

// ---------------------------------------------------------------------------
// k_prep: (a) init emax; (b) pack W into f16 hi/lo B-fragment layout
// (same layout as hpack). hi=f16(w), lo=f16(w-hi): 3-term f16 MFMA emulates
// fp32 GEMM to ~2^-20.
// ---------------------------------------------------------------------------
__global__ __launch_bounds__(256) void k_prep(const float* __restrict__ W,
                                              unsigned short* __restrict__ wph,
                                              unsigned short* __restrict__ wpl,
                                              unsigned* __restrict__ emax_u) {
  const int gid = blockIdx.x * 256 + threadIdx.x;   // 512 blocks -> 131072
  if (gid == 0) *emax_u = 0u;
  const int k = gid >> 8;          // 0..511
  const int c = gid & 255;         // 0..255
  const float w = W[(size_t)k * F_OUT + c];
  const _Float16 hi = (_Float16)w;
  const _Float16 lo = (_Float16)(w - (float)hi);
  const size_t idx =
      (((size_t)(k >> 5) * 16 + (c >> 4)) * 64 + (c & 15) + 16 * ((k >> 3) & 3)) * 8 +
      (k & 7);
  wph[idx] = *(const unsigned short*)&hi;
  wpl[idx] = *(const unsigned short*)&lo;
}

// ---------------------------------------------------------------------------
// k_hgemm (r9, proven): h = x@W via split-f16 MFMA. Unchanged this round.
// ---------------------------------------------------------------------------
__global__ __launch_bounds__(512) void k_hgemm(const float* __restrict__ x,
                                               const uint4* __restrict__ wph4,
                                               const uint4* __restrict__ wpl4,
                                               const float* __restrict__ a,
                                               unsigned short* __restrict__ hpack,
                                               float* __restrict__ EI,
                                               float* __restrict__ EJ,
                                               unsigned* __restrict__ emax_u) {
  __shared__ float eip[4][32], ejp[4][32], emx[32];
  const int r0   = blockIdx.x * 32;
  const int tid  = threadIdx.x;
  const int wid  = tid >> 6, lane = tid & 63;
  const int mg   = wid >> 2, ng = wid & 3;      // 2 row-groups x 4 col-groups
  const int lo16 = lane & 15, hi4 = lane >> 4;

  const float* xrow = x + (size_t)(r0 + mg * 16 + lo16) * F_IN + hi4 * 8;
  const uint4* whb = wph4 + (size_t)(ng * 4) * 64 + lane;  // + (ks*16+nf)*64
  const uint4* wlb = wpl4 + (size_t)(ng * 4) * 64 + lane;

  f32x4 acc[4] = {};

  float4 xa = *(const float4*)(xrow);
  float4 xb = *(const float4*)(xrow + 4);
  uint4 wh[4], wl[4];
#pragma unroll
  for (int nf = 0; nf < 4; ++nf) {
    wh[nf] = whb[(size_t)nf * 64];
    wl[nf] = wlb[(size_t)nf * 64];
  }

#pragma unroll
  for (int ks = 0; ks < 16; ++ks) {
    H8U4 ah, al;
    const float v[8] = {xa.x, xa.y, xa.z, xa.w, xb.x, xb.y, xb.z, xb.w};
#pragma unroll
    for (int j = 0; j < 8; ++j) {
      const _Float16 h = (_Float16)v[j];
      ah.h[j] = h;
      al.h[j] = (_Float16)(v[j] - (float)h);
    }
    if (ks + 1 < 16) {
      xa = *(const float4*)(xrow + (ks + 1) * 32);
      xb = *(const float4*)(xrow + (ks + 1) * 32 + 4);
    }
#pragma unroll
    for (int nf = 0; nf < 4; ++nf) {
      H8U4 bh, bl;
      bh.u = wh[nf];
      bl.u = wl[nf];
      acc[nf] = __builtin_amdgcn_mfma_f32_16x16x32_f16(ah.h, bh.h, acc[nf], 0, 0, 0);
      acc[nf] = __builtin_amdgcn_mfma_f32_16x16x32_f16(al.h, bh.h, acc[nf], 0, 0, 0);
      acc[nf] = __builtin_amdgcn_mfma_f32_16x16x32_f16(ah.h, bl.h, acc[nf], 0, 0, 0);
    }
    if (ks + 1 < 16) {
#pragma unroll
      for (int nf = 0; nf < 4; ++nf) {
        wh[nf] = whb[(size_t)((ks + 1) * 16 + nf) * 64];
        wl[nf] = wlb[(size_t)((ks + 1) * 16 + nf) * 64];
      }
    }
  }

  float asv[4], adv[4];
#pragma unroll
  for (int nf = 0; nf < 4; ++nf) {
    const int c = ng * 64 + nf * 16 + lo16;
    asv[nf] = a[c];
    adv[nf] = a[F_OUT + c];
  }
#pragma unroll
  for (int q = 0; q < 4; ++q) {
    float s1 = acc[0][q] * asv[0] + acc[1][q] * asv[1] + acc[2][q] * asv[2] +
               acc[3][q] * asv[3];
    float s2 = acc[0][q] * adv[0] + acc[1][q] * adv[1] + acc[2][q] * adv[2] +
               acc[3][q] * adv[3];
#pragma unroll
    for (int o = 1; o < 16; o <<= 1) {
      s1 += __shfl_xor(s1, o);
      s2 += __shfl_xor(s2, o);
    }
    if (lo16 == 0) {
      const int rl = mg * 16 + hi4 * 4 + q;
      eip[ng][rl] = s1;
      ejp[ng][rl] = s2;
    }
  }

#pragma unroll
  for (int nf = 0; nf < 4; ++nf) {
#pragma unroll
    for (int q = 0; q < 4; ++q) {
      const int row = r0 + mg * 16 + hi4 * 4 + q;
      const int col = ng * 64 + nf * 16 + lo16;
      const size_t idx =
          (((size_t)(row >> 5) * 16 + (col >> 4)) * 64 + (col & 15) +
           16 * ((row >> 3) & 3)) * 8 + (row & 7);
      const _Float16 hv = (_Float16)acc[nf][q];
      hpack[idx] = *(const unsigned short*)&hv;
    }
  }

  __syncthreads();
  if (tid < 32) {
    const float s1 = eip[0][tid] + eip[1][tid] + eip[2][tid] + eip[3][tid];
    const float s2 = ejp[0][tid] + ejp[1][tid] + ejp[2][tid] + ejp[3][tid];
    const int row = r0 + tid;
    EI[row] = s1 * LOG2E;
    const float e2 = s2 * LOG2E;
    EJ[row] = e2;
    emx[tid] = e2;
  }
  __syncthreads();
  if (tid == 0) {
    float m = emx[0];
#pragma unroll
    for (int i = 1; i < 32; ++i) m = fmaxf(m, emx[i]);
    unsigned b = __float_as_uint(m);
    unsigned u = (b & 0x80000000u) ? ~b : (b | 0x80000000u);
    atomicMax(emax_u, u);
  }
}

// ---------------------------------------------------------------------------
// k_pv r10: r7's proven 2-barrier skeleton, but B-fragments staged into a
// double-buffered 64KB LDS region via global_load_lds (tile t+1 staged during
// tile t -> full-tile latency cover; counted vmcnt, never drained to 0 in
// steady state). Frees 32 persistent VGPRs (b00..b13) that had us at the
// 128-reg launch_bounds cap, halves hpack L2 traffic (mg-pair duplication
// now served by LDS). EJ moves from 16KB LDS to depth-2 register prefetch.
// LDS total ~73KB -> still 2 blocks/CU.
// ---------------------------------------------------------------------------
__global__ __launch_bounds__(512, 4) void k_pv(const int* __restrict__ adj,
                                               const uint4* __restrict__ hp4,
                                               const float* __restrict__ EI,
                                               const float* __restrict__ EJ,
                                               const unsigned* __restrict__ emax_u,
                                               float* __restrict__ npart,
                                               float* __restrict__ dpart,
                                               int ntiles) {
  __shared__ __align__(16) uint4 ps4[8 * 64];     // 8 KB P tile (A-frag layout)
  __shared__ __align__(16) uint4 bs[2][2048];     // 64 KB B double-buffer
  __shared__ float A1[64], A2[64], den[64];
  const int rowbase = blockIdx.x * 64;
  const int split   = blockIdx.y;
  const int jt0     = split * ntiles;
  const int tid     = threadIdx.x;
  const int wid  = tid >> 6, lane = tid & 63;
  const int lo   = lane & 15, hi = lane >> 4;

  float EMAX;
  {
    const unsigned u = *emax_u;
    EMAX = (u & 0x80000000u) ? __uint_as_float(u & 0x7fffffffu) : __uint_as_float(~u);
  }
  if (tid < 64) {
    const float e  = EI[rowbase + tid];
    const float s  = e + EMAX;
    const float mi = fmaxf(s, 0.2f * s);
    A1[tid] = e - mi;
    A2[tid] = 0.2f * e - mi;
    den[tid] = 0.f;
  }

  // P-writer role: slot wid = ksw*4 + msub.
  const int msub = wid & 3, ksw = wid >> 2;
  const int row_p = msub * 16 + lo;
  const int jloc  = ksw * 32 + hi * 8;
  const int*   adjp = adj + (size_t)(rowbase + row_p) * N_NODES + jt0 * 64 + jloc;
  const float* ejg  = EJ + jt0 * 64 + jloc;
  // MFMA-reader role: wave (mg,ng) owns rows [mg*32,+32) x cols [ng*64,+64).
  const int mg = wid >> 2, ng = wid & 3;

  f32x4 acc[2][4] = {};
  float dacc = 0.f;

  // B staging: LDS slot s <- hp4[tile*2048 + s]; wave wid stages slices
  // s = (c*8+wid)*64 + lane for c=0..3 (wave-uniform LDS base, lane*16B).
  auto stageB = [&](int tile) {
    const uint4* gb = hp4 + (size_t)(jt0 + tile) * 2048;
    uint4* lb = &bs[tile & 1][0];
#pragma unroll
    for (int c = 0; c < 4; ++c) {
      const int s0 = (c * 8 + wid) * 64;
      glds16(gb + s0 + lane, lb + s0);
    }
  };

  // ---- prologue: stage B(0); adj depth-2; EJ depth-2 ----
  stageB(0);
  i32x4 cur0 = __builtin_nontemporal_load((const i32x4*)(adjp));
  i32x4 cur1 = __builtin_nontemporal_load((const i32x4*)(adjp + 4));
  i32x4 nxt0 = {0, 0, 0, 0}, nxt1 = {0, 0, 0, 0};
  float4 ejc0 = *(const float4*)(ejg);
  float4 ejc1 = *(const float4*)(ejg + 4);
  float4 ejn0 = {0, 0, 0, 0}, ejn1 = {0, 0, 0, 0};
  if (ntiles > 1) {
    nxt0 = __builtin_nontemporal_load((const i32x4*)(adjp + 64));
    nxt1 = __builtin_nontemporal_load((const i32x4*)(adjp + 68));
    ejn0 = *(const float4*)(ejg + 64);
    ejn1 = *(const float4*)(ejg + 68);
  }
  __syncthreads();   // A1/A2/den ready

  const float a1r = A1[row_p], a2r = A2[row_p];

  for (int jt = 0; jt < ntiles; ++jt) {
    // ---- P compute (adj + EJ already in regs) ----
    float eh[8];
    eh[0]=ejc0.x; eh[1]=ejc0.y; eh[2]=ejc0.z; eh[3]=ejc0.w;
    eh[4]=ejc1.x; eh[5]=ejc1.y; eh[6]=ejc1.z; eh[7]=ejc1.w;
    const int am[8] = {cur0.x, cur0.y, cur0.z, cur0.w, cur1.x, cur1.y, cur1.z, cur1.w};
    float ph[8];
#pragma unroll
    for (int j = 0; j < 8; ++j) {
      const float s = fmaxf(eh[j] + a1r, 0.2f * eh[j] + a2r);
      const float p = __builtin_amdgcn_exp2f(s);
      ph[j] = (am[j] > 0) ? p : 0.f;
    }
    dacc += ((ph[0] + ph[1]) + (ph[2] + ph[3])) + ((ph[4] + ph[5]) + (ph[6] + ph[7]));
    H2U q0, q1, q2, q3;
    q0.h = __builtin_amdgcn_cvt_pkrtz(ph[0], ph[1]);
    q1.h = __builtin_amdgcn_cvt_pkrtz(ph[2], ph[3]);
    q2.h = __builtin_amdgcn_cvt_pkrtz(ph[4], ph[5]);
    q3.h = __builtin_amdgcn_cvt_pkrtz(ph[6], ph[7]);
    uint4 pk = {q0.u, q1.u, q2.u, q3.u};

    asm volatile("" ::: "memory");
    __builtin_amdgcn_s_barrier();   // all waves past MFMA(jt-1): ps4 + bs safe
    asm volatile("" ::: "memory");
    ps4[wid * 64 + lane] = pk;

    // Stage B(jt+1) into the other LDS buffer (overwrites B(jt-1)'s slot).
    if (jt + 1 < ntiles) stageB(jt + 1);
    // Rotate + issue depth-2 adj / EJ prefetch.
    cur0 = nxt0; cur1 = nxt1; ejc0 = ejn0; ejc1 = ejn1;
    if (jt + 2 < ntiles) {
      const int* ap = adjp + (jt + 2) * 64;
      nxt0 = __builtin_nontemporal_load((const i32x4*)ap);
      nxt1 = __builtin_nontemporal_load((const i32x4*)(ap + 4));
      ejn0 = *(const float4*)(ejg + (jt + 2) * 64);
      ejn1 = *(const float4*)(ejg + (jt + 2) * 64 + 4);
    }

    asm volatile("s_waitcnt lgkmcnt(0)" ::: "memory");  // my ds_write visible
    // Counted vmcnt: guarantee stage(jt) retired (in-order vmcnt), while
    // leaving stage(jt+1)+adj(jt+2)+EJ(jt+2) in flight.
    if (jt + 1 < ntiles) {
      if (jt + 2 < ntiles) asm volatile("s_waitcnt vmcnt(12)" ::: "memory");
      else                 asm volatile("s_waitcnt vmcnt(8)"  ::: "memory");
    } else {
      asm volatile("s_waitcnt vmcnt(0)" ::: "memory");
    }
    __builtin_amdgcn_s_barrier();   // P tile + B tile ready
    asm volatile("" ::: "memory");

    // ---- MFMA(jt): A from ps4, B from bs[jt&1] ----
    H8U4 a00, a01, a10, a11;
    a00.u = ps4[(0 * 4 + mg * 2 + 0) * 64 + lane];
    a10.u = ps4[(0 * 4 + mg * 2 + 1) * 64 + lane];
    a01.u = ps4[(1 * 4 + mg * 2 + 0) * 64 + lane];
    a11.u = ps4[(1 * 4 + mg * 2 + 1) * 64 + lane];
    const uint4* bb = &bs[jt & 1][(ng * 4) * 64 + lane];
    H8U4 b;
    __builtin_amdgcn_s_setprio(1);
    b.u = bb[0 * 1024 + 0 * 64];
    acc[0][0] = __builtin_amdgcn_mfma_f32_16x16x32_f16(a00.h, b.h, acc[0][0], 0, 0, 0);
    acc[1][0] = __builtin_amdgcn_mfma_f32_16x16x32_f16(a10.h, b.h, acc[1][0], 0, 0, 0);
    b.u = bb[0 * 1024 + 1 * 64];
    acc[0][1] = __builtin_amdgcn_mfma_f32_16x16x32_f16(a00.h, b.h, acc[0][1], 0, 0, 0);
    acc[1][1] = __builtin_amdgcn_mfma_f32_16x16x32_f16(a10.h, b.h, acc[1][1], 0, 0, 0);
    b.u = bb[0 * 1024 + 2 * 64];
    acc[0][2] = __builtin_amdgcn_mfma_f32_16x16x32_f16(a00.h, b.h, acc[0][2], 0, 0, 0);
    acc[1][2] = __builtin_amdgcn_mfma_f32_16x16x32_f16(a10.h, b.h, acc[1][2], 0, 0, 0);
    b.u = bb[0 * 1024 + 3 * 64];
    acc[0][3] = __builtin_amdgcn_mfma_f32_16x16x32_f16(a00.h, b.h, acc[0][3], 0, 0, 0);
    acc[1][3] = __builtin_amdgcn_mfma_f32_16x16x32_f16(a10.h, b.h, acc[1][3], 0, 0, 0);
    b.u = bb[1 * 1024 + 0 * 64];
    acc[0][0] = __builtin_amdgcn_mfma_f32_16x16x32_f16(a01.h, b.h, acc[0][0], 0, 0, 0);
    acc[1][0] = __builtin_amdgcn_mfma_f32_16x16x32_f16(a11.h, b.h, acc[1][0], 0, 0, 0);
    b.u = bb[1 * 1024 + 1 * 64];
    acc[0][1] = __builtin_amdgcn_mfma_f32_16x16x32_f16(a01.h, b.h, acc[0][1], 0, 0, 0);
    acc[1][1] = __builtin_amdgcn_mfma_f32_16x16x32_f16(a11.h, b.h, acc[1][1], 0, 0, 0);
    b.u = bb[1 * 1024 + 2 * 64];
    acc[0][2] = __builtin_amdgcn_mfma_f32_16x16x32_f16(a01.h, b.h, acc[0][2], 0, 0, 0);
    acc[1][2] = __builtin_amdgcn_mfma_f32_16x16x32_f16(a11.h, b.h, acc[1][2], 0, 0, 0);
    b.u = bb[1 * 1024 + 3 * 64];
    acc[0][3] = __builtin_amdgcn_mfma_f32_16x16x32_f16(a01.h, b.h, acc[0][3], 0, 0, 0);
    acc[1][3] = __builtin_amdgcn_mfma_f32_16x16x32_f16(a11.h, b.h, acc[1][3], 0, 0, 0);
    __builtin_amdgcn_s_setprio(0);
  }

  atomicAdd(&den[row_p], dacc);
  __syncthreads();

  float* npb = npart + (size_t)split * N_NODES * F_OUT;
#pragma unroll
  for (int mi_ = 0; mi_ < 2; ++mi_) {
    const int rb = rowbase + (mg * 2 + mi_) * 16 + hi * 4;
#pragma unroll
    for (int nf = 0; nf < 4; ++nf) {
      const int col = ng * 64 + nf * 16 + lo;
#pragma unroll
      for (int r2 = 0; r2 < 4; ++r2)
        __builtin_nontemporal_store(acc[mi_][nf][r2],
                                    &npb[(size_t)(rb + r2) * F_OUT + col]);
    }
  }
  if (tid < 64)
    __builtin_nontemporal_store(den[tid],
                                &dpart[(size_t)split * N_NODES + rowbase + tid]);
}

// ---------------------------------------------------------------------------
// k_fin: combine splits, divide by denom, ELU, write output.
// ---------------------------------------------------------------------------
__global__ __launch_bounds__(256) void k_fin(const float* __restrict__ npart,
                                             const float* __restrict__ dpart,
                                             float* __restrict__ out,
                                             int nsplit) {
  const int gid = blockIdx.x * 256 + threadIdx.x;
  const int row = gid >> 6;
  const int c4  = (gid & 63) << 2;
  f32x4 s = {0.f, 0.f, 0.f, 0.f};
  float d = 0.f;
  for (int sp = 0; sp < nsplit; ++sp) {
    const f32x4 v = __builtin_nontemporal_load(
        (const f32x4*)(npart + ((size_t)sp * N_NODES + row) * F_OUT + c4));
    s += v;
    d += dpart[(size_t)sp * N_NODES + row];
  }
  const float inv = 1.f / d;
  float o[4] = {s.x * inv, s.y * inv, s.z * inv, s.w * inv};
#pragma unroll
  for (int i = 0; i < 4; ++i) o[i] = (o[i] > 0.f) ? o[i] : expm1f(o[i]);
  float4 ov = {o[0], o[1], o[2], o[3]};
  *(float4*)(out + (size_t)row * F_OUT + c4) = ov;
}

// ---------------------------------------------------------------------------
extern "C" void kernel_launch(void* const* d_in, const int* in_sizes, int n_in,
                              void* d_out, int out_size, void* d_ws, size_t ws_size,
                              hipStream_t stream) {
  const float* x   = (const float*)d_in[0];
  const int*   adj = (const int*)d_in[1];
  const float* W   = (const float*)d_in[2];
  const float* a   = (const float*)d_in[3];
  float* out = (float*)d_out;
  char*  ws  = (char*)d_ws;

  unsigned short* hpack = (unsigned short*)ws;  // 4 MB, B-fragment layout
  size_t off = (size_t)4 * 1024 * 1024;
  float* EI = (float*)(ws + off); off += (size_t)N_NODES * 4;
  float* EJ = (float*)(ws + off); off += (size_t)N_NODES * 4;
  unsigned* emax_u = (unsigned*)(ws + off); off += 256;
  float* dpart = (float*)(ws + off); off += (size_t)8 * N_NODES * 4;
  unsigned short* wph = (unsigned short*)(ws + off); off += (size_t)F_IN * F_OUT * 2;
  unsigned short* wpl = (unsigned short*)(ws + off); off += (size_t)F_IN * F_OUT * 2;
  float* npart = (float*)(ws + off);

  int nsplit = 4;   // 512 blocks: all co-resident in one dispatch round (r6 lesson)
  while (nsplit > 1 && off + (size_t)nsplit * N_NODES * F_OUT * 4 > ws_size) nsplit >>= 1;

  k_prep<<<dim3((F_IN * F_OUT) / 256), dim3(256), 0, stream>>>(W, wph, wpl, emax_u);
  k_hgemm<<<dim3(N_NODES / 32), dim3(512), 0, stream>>>(
      x, (const uint4*)wph, (const uint4*)wpl, a, hpack, EI, EJ, emax_u);
  k_pv<<<dim3(128, nsplit), dim3(512), 0, stream>>>(adj, (const uint4*)hpack, EI, EJ,
                                                    emax_u, npart, dpart, 128 / nsplit);
  k_fin<<<dim3(N_NODES * 64 / 256), dim3(256), 0, stream>>>(npart, dpart, out, nsplit);
}

// Round 4
// 144.455 us; speedup vs baseline: 1.0671x; 1.0671x over previous
//
#include <hip/hip_runtime.h>
#include <hip/hip_fp16.h>

#define N_NODES 8192
#define F_IN    512
#define F_OUT   256
#define LOG2E   1.4426950408889634f

typedef __attribute__((ext_vector_type(8))) _Float16 half8;
typedef __attribute__((ext_vector_type(2))) __fp16   fp16x2;
typedef __attribute__((ext_vector_type(4))) float    f32x4;

union H8U4 { half8 h; uint4 u; };
union H2U  { fp16x2 h; unsigned u; };

// ---------------------------------------------------------------------------
// k_badj: compress adj (268 MB int32) -> row-major bitmask (8 MB).
// Wave reads 64 consecutive ints (256B coalesced, nontemporal), __ballot
// packs 64 lanes -> u64 whose byte k holds bits j=8k..8k+7 (little-endian),
// matching k_pv's per-lane byte addressing. 4 chunks/wave-iter, uint4 stores.
// Pure streaming pass -> should run at fill-kernel BW (~45us).
// ---------------------------------------------------------------------------
__global__ __launch_bounds__(256) void k_badj(const int* __restrict__ adj,
                                              unsigned long long* __restrict__ bm) {
  const int nw   = (gridDim.x * 256) >> 6;
  const int gw   = (blockIdx.x * 256 + threadIdx.x) >> 6;
  const int lane = threadIdx.x & 63;
  const int nchunk = N_NODES * (N_NODES / 64);
  for (int c0 = gw * 4; c0 < nchunk; c0 += nw * 4) {
    const size_t base = (size_t)c0 * 64 + lane;
    const int v0 = __builtin_nontemporal_load(adj + base);
    const int v1 = __builtin_nontemporal_load(adj + base + 64);
    const int v2 = __builtin_nontemporal_load(adj + base + 128);
    const int v3 = __builtin_nontemporal_load(adj + base + 192);
    const unsigned long long m0 = __ballot(v0 > 0);
    const unsigned long long m1 = __ballot(v1 > 0);
    const unsigned long long m2 = __ballot(v2 > 0);
    const unsigned long long m3 = __ballot(v3 > 0);
    if (lane == 0) {
      uint4 s0, s1;
      s0.x = (unsigned)m0; s0.y = (unsigned)(m0 >> 32);
      s0.z = (unsigned)m1; s0.w = (unsigned)(m1 >> 32);
      s1.x = (unsigned)m2; s1.y = (unsigned)(m2 >> 32);
      s1.z = (unsigned)m3; s1.w = (unsigned)(m3 >> 32);
      *(uint4*)(bm + c0)     = s0;
      *(uint4*)(bm + c0 + 2) = s1;
    }
  }
}

// ---------------------------------------------------------------------------
// k_prep: (a) init emax; (b) pack W into f16 hi/lo B-fragment layout
// (same layout as hpack). hi=f16(w), lo=f16(w-hi): 3-term f16 MFMA emulates
// fp32 GEMM to ~2^-20.
// ---------------------------------------------------------------------------
__global__ __launch_bounds__(256) void k_prep(const float* __restrict__ W,
                                              unsigned short* __restrict__ wph,
                                              unsigned short* __restrict__ wpl,
                                              unsigned* __restrict__ emax_u) {
  const int gid = blockIdx.x * 256 + threadIdx.x;   // 512 blocks -> 131072
  if (gid == 0) *emax_u = 0u;
  const int k = gid >> 8;          // 0..511
  const int c = gid & 255;         // 0..255
  const float w = W[(size_t)k * F_OUT + c];
  const _Float16 hi = (_Float16)w;
  const _Float16 lo = (_Float16)(w - (float)hi);
  const size_t idx =
      (((size_t)(k >> 5) * 16 + (c >> 4)) * 64 + (c & 15) + 16 * ((k >> 3) & 3)) * 8 +
      (k & 7);
  wph[idx] = *(const unsigned short*)&hi;
  wpl[idx] = *(const unsigned short*)&lo;
}

// ---------------------------------------------------------------------------
// k_hgemm (r9, proven): h = x@W via split-f16 MFMA. Unchanged this round.
// ---------------------------------------------------------------------------
__global__ __launch_bounds__(512) void k_hgemm(const float* __restrict__ x,
                                               const uint4* __restrict__ wph4,
                                               const uint4* __restrict__ wpl4,
                                               const float* __restrict__ a,
                                               unsigned short* __restrict__ hpack,
                                               float* __restrict__ EI,
                                               float* __restrict__ EJ,
                                               unsigned* __restrict__ emax_u) {
  __shared__ float eip[4][32], ejp[4][32], emx[32];
  const int r0   = blockIdx.x * 32;
  const int tid  = threadIdx.x;
  const int wid  = tid >> 6, lane = tid & 63;
  const int mg   = wid >> 2, ng = wid & 3;      // 2 row-groups x 4 col-groups
  const int lo16 = lane & 15, hi4 = lane >> 4;

  const float* xrow = x + (size_t)(r0 + mg * 16 + lo16) * F_IN + hi4 * 8;
  const uint4* whb = wph4 + (size_t)(ng * 4) * 64 + lane;  // + (ks*16+nf)*64
  const uint4* wlb = wpl4 + (size_t)(ng * 4) * 64 + lane;

  f32x4 acc[4] = {};

  float4 xa = *(const float4*)(xrow);
  float4 xb = *(const float4*)(xrow + 4);
  uint4 wh[4], wl[4];
#pragma unroll
  for (int nf = 0; nf < 4; ++nf) {
    wh[nf] = whb[(size_t)nf * 64];
    wl[nf] = wlb[(size_t)nf * 64];
  }

#pragma unroll
  for (int ks = 0; ks < 16; ++ks) {
    H8U4 ah, al;
    const float v[8] = {xa.x, xa.y, xa.z, xa.w, xb.x, xb.y, xb.z, xb.w};
#pragma unroll
    for (int j = 0; j < 8; ++j) {
      const _Float16 h = (_Float16)v[j];
      ah.h[j] = h;
      al.h[j] = (_Float16)(v[j] - (float)h);
    }
    if (ks + 1 < 16) {
      xa = *(const float4*)(xrow + (ks + 1) * 32);
      xb = *(const float4*)(xrow + (ks + 1) * 32 + 4);
    }
#pragma unroll
    for (int nf = 0; nf < 4; ++nf) {
      H8U4 bh, bl;
      bh.u = wh[nf];
      bl.u = wl[nf];
      acc[nf] = __builtin_amdgcn_mfma_f32_16x16x32_f16(ah.h, bh.h, acc[nf], 0, 0, 0);
      acc[nf] = __builtin_amdgcn_mfma_f32_16x16x32_f16(al.h, bh.h, acc[nf], 0, 0, 0);
      acc[nf] = __builtin_amdgcn_mfma_f32_16x16x32_f16(ah.h, bl.h, acc[nf], 0, 0, 0);
    }
    if (ks + 1 < 16) {
#pragma unroll
      for (int nf = 0; nf < 4; ++nf) {
        wh[nf] = whb[(size_t)((ks + 1) * 16 + nf) * 64];
        wl[nf] = wlb[(size_t)((ks + 1) * 16 + nf) * 64];
      }
    }
  }

  float asv[4], adv[4];
#pragma unroll
  for (int nf = 0; nf < 4; ++nf) {
    const int c = ng * 64 + nf * 16 + lo16;
    asv[nf] = a[c];
    adv[nf] = a[F_OUT + c];
  }
#pragma unroll
  for (int q = 0; q < 4; ++q) {
    float s1 = acc[0][q] * asv[0] + acc[1][q] * asv[1] + acc[2][q] * asv[2] +
               acc[3][q] * asv[3];
    float s2 = acc[0][q] * adv[0] + acc[1][q] * adv[1] + acc[2][q] * adv[2] +
               acc[3][q] * adv[3];
#pragma unroll
    for (int o = 1; o < 16; o <<= 1) {
      s1 += __shfl_xor(s1, o);
      s2 += __shfl_xor(s2, o);
    }
    if (lo16 == 0) {
      const int rl = mg * 16 + hi4 * 4 + q;
      eip[ng][rl] = s1;
      ejp[ng][rl] = s2;
    }
  }

#pragma unroll
  for (int nf = 0; nf < 4; ++nf) {
#pragma unroll
    for (int q = 0; q < 4; ++q) {
      const int row = r0 + mg * 16 + hi4 * 4 + q;
      const int col = ng * 64 + nf * 16 + lo16;
      const size_t idx =
          (((size_t)(row >> 5) * 16 + (col >> 4)) * 64 + (col & 15) +
           16 * ((row >> 3) & 3)) * 8 + (row & 7);
      const _Float16 hv = (_Float16)acc[nf][q];
      hpack[idx] = *(const unsigned short*)&hv;
    }
  }

  __syncthreads();
  if (tid < 32) {
    const float s1 = eip[0][tid] + eip[1][tid] + eip[2][tid] + eip[3][tid];
    const float s2 = ejp[0][tid] + ejp[1][tid] + ejp[2][tid] + ejp[3][tid];
    const int row = r0 + tid;
    EI[row] = s1 * LOG2E;
    const float e2 = s2 * LOG2E;
    EJ[row] = e2;
    emx[tid] = e2;
  }
  __syncthreads();
  if (tid == 0) {
    float m = emx[0];
#pragma unroll
    for (int i = 1; i < 32; ++i) m = fmaxf(m, emx[i]);
    unsigned b = __float_as_uint(m);
    unsigned u = (b & 0x80000000u) ? ~b : (b | 0x80000000u);
    atomicMax(emax_u, u);
  }
}

// ---------------------------------------------------------------------------
// k_pv r11: exact R2 (148.7us) structure, with adj int32 loads replaced by
// bitmask uchar loads (32x less traffic; same depth-2 prefetch skeleton).
// Per lane per tile: 1 byte covering its 8 j-values; bit test replaces
// (am[j]>0). Frees 14 VGPR. Everything else byte-identical to the proven r7
// skeleton: 2-barrier pipeline, 8 B-frag register loads, LDS EJ, setprio MFMA.
// ---------------------------------------------------------------------------
__global__ __launch_bounds__(512, 4) void k_pv(const unsigned char* __restrict__ bmask,
                                               const uint4* __restrict__ hp4,
                                               const float* __restrict__ EI,
                                               const float* __restrict__ EJ,
                                               const unsigned* __restrict__ emax_u,
                                               float* __restrict__ npart,
                                               float* __restrict__ dpart,
                                               int ntiles) {
  __shared__ __align__(16) uint4 ps4[8 * 64];   // 8 KB P tile (A-fragment layout)
  __shared__ float ejhi[2048], ejlo[2048];      // split's EJ, 0.2*EJ
  __shared__ float A1[64], A2[64], den[64];
  const int rowbase = blockIdx.x * 64;
  const int split   = blockIdx.y;
  const int jt0     = split * ntiles;
  const int tid     = threadIdx.x;
  const int wid  = tid >> 6, lane = tid & 63;
  const int lo   = lane & 15, hi = lane >> 4;

  float EMAX;
  {
    const unsigned u = *emax_u;
    EMAX = (u & 0x80000000u) ? __uint_as_float(u & 0x7fffffffu) : __uint_as_float(~u);
  }
  if (tid < 64) {
    const float e  = EI[rowbase + tid];
    const float s  = e + EMAX;
    const float mi = fmaxf(s, 0.2f * s);
    A1[tid] = e - mi;
    A2[tid] = 0.2f * e - mi;
    den[tid] = 0.f;
  }
  const bool uselds = (ntiles <= 32);
  if (uselds) {
    int eidx = jt0 * 64 + tid * 4;              // clamp guard (no-op at nsplit=4)
    if (eidx > N_NODES - 4) eidx = N_NODES - 4;
    const float4 ev = *(const float4*)&EJ[eidx];
    *(float4*)&ejhi[tid * 4] = ev;
    float4 el = {0.2f * ev.x, 0.2f * ev.y, 0.2f * ev.z, 0.2f * ev.w};
    *(float4*)&ejlo[tid * 4] = el;
  }
  __syncthreads();

  // P-writer role: slot wid = ksw*4 + msub.
  const int msub = wid & 3, ksw = wid >> 2;
  const int row_p = msub * 16 + lo;
  const int jloc  = ksw * 32 + hi * 8;
  const float a1r = A1[row_p], a2r = A2[row_p];
  // Bitmask: byte (r*1024 + j/8); this lane's window starts at jt0*64+jloc.
  const unsigned char* mbp =
      bmask + (size_t)(rowbase + row_p) * (N_NODES / 8) + (size_t)jt0 * 8 + ksw * 4 + hi;
  const float* ejg  = EJ + jt0 * 64 + jloc;
  // MFMA-reader role: wave (mg,ng) owns rows [mg*32,+32) x cols [ng*64,+64).
  const int mg = wid >> 2, ng = wid & 3;
  const uint4* hb = hp4 + (ng * 4) * 64 + lane;

  f32x4 acc[2][4] = {};
  float dacc = 0.f;

  unsigned mcur = mbp[0];
  unsigned mnxt = (ntiles > 1) ? (unsigned)mbp[8] : 0u;

  for (int jt = 0; jt < ntiles; ++jt) {
    const int tb = (jt0 + jt) * 2048;  // uint4 offset of this tile's first k-block
    // B fragments for this tile (L2/L3-hot).
    const uint4 b00 = hb[tb + 0 * 1024 + 0 * 64];
    const uint4 b01 = hb[tb + 0 * 1024 + 1 * 64];
    const uint4 b02 = hb[tb + 0 * 1024 + 2 * 64];
    const uint4 b03 = hb[tb + 0 * 1024 + 3 * 64];
    const uint4 b10 = hb[tb + 1 * 1024 + 0 * 64];
    const uint4 b11 = hb[tb + 1 * 1024 + 1 * 64];
    const uint4 b12 = hb[tb + 1 * 1024 + 2 * 64];
    const uint4 b13 = hb[tb + 1 * 1024 + 3 * 64];

    // P compute: 8 values/thread.
    float eh[8], el[8];
    if (uselds) {
      const float4 h0 = *(const float4*)&ejhi[jt * 64 + jloc];
      const float4 h1 = *(const float4*)&ejhi[jt * 64 + jloc + 4];
      const float4 l0 = *(const float4*)&ejlo[jt * 64 + jloc];
      const float4 l1 = *(const float4*)&ejlo[jt * 64 + jloc + 4];
      eh[0]=h0.x; eh[1]=h0.y; eh[2]=h0.z; eh[3]=h0.w;
      eh[4]=h1.x; eh[5]=h1.y; eh[6]=h1.z; eh[7]=h1.w;
      el[0]=l0.x; el[1]=l0.y; el[2]=l0.z; el[3]=l0.w;
      el[4]=l1.x; el[5]=l1.y; el[6]=l1.z; el[7]=l1.w;
    } else {
      const float4 e0 = *(const float4*)(ejg + jt * 64);
      const float4 e1 = *(const float4*)(ejg + jt * 64 + 4);
      eh[0]=e0.x; eh[1]=e0.y; eh[2]=e0.z; eh[3]=e0.w;
      eh[4]=e1.x; eh[5]=e1.y; eh[6]=e1.z; eh[7]=e1.w;
#pragma unroll
      for (int j = 0; j < 8; ++j) el[j] = 0.2f * eh[j];
    }
    float ph[8];
#pragma unroll
    for (int j = 0; j < 8; ++j) {
      const float s = fmaxf(eh[j] + a1r, el[j] + a2r);
      const float p = __builtin_amdgcn_exp2f(s);
      ph[j] = (mcur & (1u << j)) ? p : 0.f;
    }
    dacc += ((ph[0] + ph[1]) + (ph[2] + ph[3])) + ((ph[4] + ph[5]) + (ph[6] + ph[7]));
    H2U q0, q1, q2, q3;
    q0.h = __builtin_amdgcn_cvt_pkrtz(ph[0], ph[1]);
    q1.h = __builtin_amdgcn_cvt_pkrtz(ph[2], ph[3]);
    q2.h = __builtin_amdgcn_cvt_pkrtz(ph[4], ph[5]);
    q3.h = __builtin_amdgcn_cvt_pkrtz(ph[6], ph[7]);
    uint4 pk = {q0.u, q1.u, q2.u, q3.u};

    asm volatile("" ::: "memory");
    __builtin_amdgcn_s_barrier();        // all waves done reading ps4 (prev tile)
    asm volatile("" ::: "memory");
    ps4[wid * 64 + lane] = pk;
    // rotate prefetch regs; issue depth-2 mask prefetch (stays in flight).
    mcur = mnxt;
    if (jt + 2 < ntiles) mnxt = (unsigned)mbp[(jt + 2) * 8];
    asm volatile("s_waitcnt lgkmcnt(0)" ::: "memory");  // my ds_write visible
    __builtin_amdgcn_s_barrier();        // P tile ready
    asm volatile("" ::: "memory");

    H8U4 a00, a01, a10, a11;
    a00.u = ps4[(0 * 4 + mg * 2 + 0) * 64 + lane];
    a10.u = ps4[(0 * 4 + mg * 2 + 1) * 64 + lane];
    a01.u = ps4[(1 * 4 + mg * 2 + 0) * 64 + lane];
    a11.u = ps4[(1 * 4 + mg * 2 + 1) * 64 + lane];
    H8U4 b;
    __builtin_amdgcn_s_setprio(1);
    b.u = b00;
    acc[0][0] = __builtin_amdgcn_mfma_f32_16x16x32_f16(a00.h, b.h, acc[0][0], 0, 0, 0);
    acc[1][0] = __builtin_amdgcn_mfma_f32_16x16x32_f16(a10.h, b.h, acc[1][0], 0, 0, 0);
    b.u = b01;
    acc[0][1] = __builtin_amdgcn_mfma_f32_16x16x32_f16(a00.h, b.h, acc[0][1], 0, 0, 0);
    acc[1][1] = __builtin_amdgcn_mfma_f32_16x16x32_f16(a10.h, b.h, acc[1][1], 0, 0, 0);
    b.u = b02;
    acc[0][2] = __builtin_amdgcn_mfma_f32_16x16x32_f16(a00.h, b.h, acc[0][2], 0, 0, 0);
    acc[1][2] = __builtin_amdgcn_mfma_f32_16x16x32_f16(a10.h, b.h, acc[1][2], 0, 0, 0);
    b.u = b03;
    acc[0][3] = __builtin_amdgcn_mfma_f32_16x16x32_f16(a00.h, b.h, acc[0][3], 0, 0, 0);
    acc[1][3] = __builtin_amdgcn_mfma_f32_16x16x32_f16(a10.h, b.h, acc[1][3], 0, 0, 0);
    b.u = b10;
    acc[0][0] = __builtin_amdgcn_mfma_f32_16x16x32_f16(a01.h, b.h, acc[0][0], 0, 0, 0);
    acc[1][0] = __builtin_amdgcn_mfma_f32_16x16x32_f16(a11.h, b.h, acc[1][0], 0, 0, 0);
    b.u = b11;
    acc[0][1] = __builtin_amdgcn_mfma_f32_16x16x32_f16(a01.h, b.h, acc[0][1], 0, 0, 0);
    acc[1][1] = __builtin_amdgcn_mfma_f32_16x16x32_f16(a11.h, b.h, acc[1][1], 0, 0, 0);
    b.u = b12;
    acc[0][2] = __builtin_amdgcn_mfma_f32_16x16x32_f16(a01.h, b.h, acc[0][2], 0, 0, 0);
    acc[1][2] = __builtin_amdgcn_mfma_f32_16x16x32_f16(a11.h, b.h, acc[1][2], 0, 0, 0);
    b.u = b13;
    acc[0][3] = __builtin_amdgcn_mfma_f32_16x16x32_f16(a01.h, b.h, acc[0][3], 0, 0, 0);
    acc[1][3] = __builtin_amdgcn_mfma_f32_16x16x32_f16(a11.h, b.h, acc[1][3], 0, 0, 0);
    __builtin_amdgcn_s_setprio(0);
  }

  atomicAdd(&den[row_p], dacc);
  __syncthreads();

  float* npb = npart + (size_t)split * N_NODES * F_OUT;
#pragma unroll
  for (int mi_ = 0; mi_ < 2; ++mi_) {
    const int rb = rowbase + (mg * 2 + mi_) * 16 + hi * 4;
#pragma unroll
    for (int nf = 0; nf < 4; ++nf) {
      const int col = ng * 64 + nf * 16 + lo;
#pragma unroll
      for (int r2 = 0; r2 < 4; ++r2)
        __builtin_nontemporal_store(acc[mi_][nf][r2],
                                    &npb[(size_t)(rb + r2) * F_OUT + col]);
    }
  }
  if (tid < 64)
    __builtin_nontemporal_store(den[tid],
                                &dpart[(size_t)split * N_NODES + rowbase + tid]);
}

// ---------------------------------------------------------------------------
// k_fin: combine splits, divide by denom, ELU, write output.
// ---------------------------------------------------------------------------
__global__ __launch_bounds__(256) void k_fin(const float* __restrict__ npart,
                                             const float* __restrict__ dpart,
                                             float* __restrict__ out,
                                             int nsplit) {
  const int gid = blockIdx.x * 256 + threadIdx.x;
  const int row = gid >> 6;
  const int c4  = (gid & 63) << 2;
  f32x4 s = {0.f, 0.f, 0.f, 0.f};
  float d = 0.f;
  for (int sp = 0; sp < nsplit; ++sp) {
    const f32x4 v = __builtin_nontemporal_load(
        (const f32x4*)(npart + ((size_t)sp * N_NODES + row) * F_OUT + c4));
    s += v;
    d += dpart[(size_t)sp * N_NODES + row];
  }
  const float inv = 1.f / d;
  float o[4] = {s.x * inv, s.y * inv, s.z * inv, s.w * inv};
#pragma unroll
  for (int i = 0; i < 4; ++i) o[i] = (o[i] > 0.f) ? o[i] : expm1f(o[i]);
  float4 ov = {o[0], o[1], o[2], o[3]};
  *(float4*)(out + (size_t)row * F_OUT + c4) = ov;
}

// ---------------------------------------------------------------------------
extern "C" void kernel_launch(void* const* d_in, const int* in_sizes, int n_in,
                              void* d_out, int out_size, void* d_ws, size_t ws_size,
                              hipStream_t stream) {
  const float* x   = (const float*)d_in[0];
  const int*   adj = (const int*)d_in[1];
  const float* W   = (const float*)d_in[2];
  const float* a   = (const float*)d_in[3];
  float* out = (float*)d_out;
  char*  ws  = (char*)d_ws;

  unsigned short* hpack = (unsigned short*)ws;  // 4 MB, B-fragment layout
  size_t off = (size_t)4 * 1024 * 1024;
  float* EI = (float*)(ws + off); off += (size_t)N_NODES * 4;
  float* EJ = (float*)(ws + off); off += (size_t)N_NODES * 4;
  unsigned* emax_u = (unsigned*)(ws + off); off += 256;
  float* dpart = (float*)(ws + off); off += (size_t)8 * N_NODES * 4;
  unsigned short* wph = (unsigned short*)(ws + off); off += (size_t)F_IN * F_OUT * 2;
  unsigned short* wpl = (unsigned short*)(ws + off); off += (size_t)F_IN * F_OUT * 2;
  unsigned long long* bmask = (unsigned long long*)(ws + off);
  off += (size_t)N_NODES * (N_NODES / 8);       // 8 MB bitmask
  float* npart = (float*)(ws + off);

  int nsplit = 4;   // 512 blocks: all co-resident in one dispatch round (r6 lesson)
  while (nsplit > 1 && off + (size_t)nsplit * N_NODES * F_OUT * 4 > ws_size) nsplit >>= 1;

  k_badj<<<dim3(2048), dim3(256), 0, stream>>>(adj, bmask);
  k_prep<<<dim3((F_IN * F_OUT) / 256), dim3(256), 0, stream>>>(W, wph, wpl, emax_u);
  k_hgemm<<<dim3(N_NODES / 32), dim3(512), 0, stream>>>(
      x, (const uint4*)wph, (const uint4*)wpl, a, hpack, EI, EJ, emax_u);
  k_pv<<<dim3(128, nsplit), dim3(512), 0, stream>>>(
      (const unsigned char*)bmask, (const uint4*)hpack, EI, EJ, emax_u, npart, dpart,
      128 / nsplit);
  k_fin<<<dim3(N_NODES * 64 / 256), dim3(256), 0, stream>>>(npart, dpart, out, nsplit);
}

// Round 5
// 141.787 us; speedup vs baseline: 1.0872x; 1.0188x over previous
//
#include <hip/hip_runtime.h>
#include <hip/hip_fp16.h>

#define N_NODES 8192
#define F_IN    512
#define F_OUT   256
#define LOG2E   1.4426950408889634f

typedef __attribute__((ext_vector_type(8))) _Float16 half8;
typedef __attribute__((ext_vector_type(2))) __fp16   fp16x2;
typedef __attribute__((ext_vector_type(4))) float    f32x4;
typedef __attribute__((ext_vector_type(4))) int      i32x4;

union H8U4 { half8 h; uint4 u; };
union H2U  { fp16x2 h; unsigned u; };

// ---------------------------------------------------------------------------
// k_prep: (a) init emax; (b) pack W into f16 hi/lo B-fragment layout
// (same layout as hpack). hi=f16(w), lo=f16(w-hi): 3-term f16 MFMA emulates
// fp32 GEMM to ~2^-20.
// ---------------------------------------------------------------------------
__global__ __launch_bounds__(256) void k_prep(const float* __restrict__ W,
                                              unsigned short* __restrict__ wph,
                                              unsigned short* __restrict__ wpl,
                                              unsigned* __restrict__ emax_u) {
  const int gid = blockIdx.x * 256 + threadIdx.x;   // 512 blocks -> 131072
  if (gid == 0) *emax_u = 0u;
  const int k = gid >> 8;          // 0..511
  const int c = gid & 255;         // 0..255
  const float w = W[(size_t)k * F_OUT + c];
  const _Float16 hi = (_Float16)w;
  const _Float16 lo = (_Float16)(w - (float)hi);
  const size_t idx =
      (((size_t)(k >> 5) * 16 + (c >> 4)) * 64 + (c & 15) + 16 * ((k >> 3) & 3)) * 8 +
      (k & 7);
  wph[idx] = *(const unsigned short*)&hi;
  wpl[idx] = *(const unsigned short*)&lo;
}

// ---------------------------------------------------------------------------
// k_hgemm (r9, proven): h = x@W via split-f16 MFMA. Unchanged this round.
// ---------------------------------------------------------------------------
__global__ __launch_bounds__(512) void k_hgemm(const float* __restrict__ x,
                                               const uint4* __restrict__ wph4,
                                               const uint4* __restrict__ wpl4,
                                               const float* __restrict__ a,
                                               unsigned short* __restrict__ hpack,
                                               float* __restrict__ EI,
                                               float* __restrict__ EJ,
                                               unsigned* __restrict__ emax_u) {
  __shared__ float eip[4][32], ejp[4][32], emx[32];
  const int r0   = blockIdx.x * 32;
  const int tid  = threadIdx.x;
  const int wid  = tid >> 6, lane = tid & 63;
  const int mg   = wid >> 2, ng = wid & 3;      // 2 row-groups x 4 col-groups
  const int lo16 = lane & 15, hi4 = lane >> 4;

  const float* xrow = x + (size_t)(r0 + mg * 16 + lo16) * F_IN + hi4 * 8;
  const uint4* whb = wph4 + (size_t)(ng * 4) * 64 + lane;  // + (ks*16+nf)*64
  const uint4* wlb = wpl4 + (size_t)(ng * 4) * 64 + lane;

  f32x4 acc[4] = {};

  float4 xa = *(const float4*)(xrow);
  float4 xb = *(const float4*)(xrow + 4);
  uint4 wh[4], wl[4];
#pragma unroll
  for (int nf = 0; nf < 4; ++nf) {
    wh[nf] = whb[(size_t)nf * 64];
    wl[nf] = wlb[(size_t)nf * 64];
  }

#pragma unroll
  for (int ks = 0; ks < 16; ++ks) {
    H8U4 ah, al;
    const float v[8] = {xa.x, xa.y, xa.z, xa.w, xb.x, xb.y, xb.z, xb.w};
#pragma unroll
    for (int j = 0; j < 8; ++j) {
      const _Float16 h = (_Float16)v[j];
      ah.h[j] = h;
      al.h[j] = (_Float16)(v[j] - (float)h);
    }
    if (ks + 1 < 16) {
      xa = *(const float4*)(xrow + (ks + 1) * 32);
      xb = *(const float4*)(xrow + (ks + 1) * 32 + 4);
    }
#pragma unroll
    for (int nf = 0; nf < 4; ++nf) {
      H8U4 bh, bl;
      bh.u = wh[nf];
      bl.u = wl[nf];
      acc[nf] = __builtin_amdgcn_mfma_f32_16x16x32_f16(ah.h, bh.h, acc[nf], 0, 0, 0);
      acc[nf] = __builtin_amdgcn_mfma_f32_16x16x32_f16(al.h, bh.h, acc[nf], 0, 0, 0);
      acc[nf] = __builtin_amdgcn_mfma_f32_16x16x32_f16(ah.h, bl.h, acc[nf], 0, 0, 0);
    }
    if (ks + 1 < 16) {
#pragma unroll
      for (int nf = 0; nf < 4; ++nf) {
        wh[nf] = whb[(size_t)((ks + 1) * 16 + nf) * 64];
        wl[nf] = wlb[(size_t)((ks + 1) * 16 + nf) * 64];
      }
    }
  }

  float asv[4], adv[4];
#pragma unroll
  for (int nf = 0; nf < 4; ++nf) {
    const int c = ng * 64 + nf * 16 + lo16;
    asv[nf] = a[c];
    adv[nf] = a[F_OUT + c];
  }
#pragma unroll
  for (int q = 0; q < 4; ++q) {
    float s1 = acc[0][q] * asv[0] + acc[1][q] * asv[1] + acc[2][q] * asv[2] +
               acc[3][q] * asv[3];
    float s2 = acc[0][q] * adv[0] + acc[1][q] * adv[1] + acc[2][q] * adv[2] +
               acc[3][q] * adv[3];
#pragma unroll
    for (int o = 1; o < 16; o <<= 1) {
      s1 += __shfl_xor(s1, o);
      s2 += __shfl_xor(s2, o);
    }
    if (lo16 == 0) {
      const int rl = mg * 16 + hi4 * 4 + q;
      eip[ng][rl] = s1;
      ejp[ng][rl] = s2;
    }
  }

#pragma unroll
  for (int nf = 0; nf < 4; ++nf) {
#pragma unroll
    for (int q = 0; q < 4; ++q) {
      const int row = r0 + mg * 16 + hi4 * 4 + q;
      const int col = ng * 64 + nf * 16 + lo16;
      const size_t idx =
          (((size_t)(row >> 5) * 16 + (col >> 4)) * 64 + (col & 15) +
           16 * ((row >> 3) & 3)) * 8 + (row & 7);
      const _Float16 hv = (_Float16)acc[nf][q];
      hpack[idx] = *(const unsigned short*)&hv;
    }
  }

  __syncthreads();
  if (tid < 32) {
    const float s1 = eip[0][tid] + eip[1][tid] + eip[2][tid] + eip[3][tid];
    const float s2 = ejp[0][tid] + ejp[1][tid] + ejp[2][tid] + ejp[3][tid];
    const int row = r0 + tid;
    EI[row] = s1 * LOG2E;
    const float e2 = s2 * LOG2E;
    EJ[row] = e2;
    emx[tid] = e2;
  }
  __syncthreads();
  if (tid == 0) {
    float m = emx[0];
#pragma unroll
    for (int i = 1; i < 32; ++i) m = fmaxf(m, emx[i]);
    unsigned b = __float_as_uint(m);
    unsigned u = (b & 0x80000000u) ? ~b : (b | 0x80000000u);
    atomicMax(emax_u, u);
  }
}

// ---------------------------------------------------------------------------
// k_pv r12: r11 skeleton, but the adj->bitmask conversion is FUSED into the
// tile pipeline (k_badj's 43us serial streaming pass eliminated). Per tile,
// each thread NT-loads 8 adj ints for (row = tid>>3, cols (tid&7)*8..+8) --
// per wave that's 8 rows x 256B contiguous segments (k_badj-class coalescing,
// not the old 16x128B scatter) -- issued in the inter-barrier window one tile
// ahead, bit-packed in registers, exchanged via a 1KB double-buffered LDS
// byte array under the existing barrier discipline (write parity (t+1)&1 in
// window t, read parity t&1 in P-phase t; two barriers separate read from
// overwrite). The 268MB adj stream now overlaps P/MFMA compute instead of
// serializing ahead of it.
// ---------------------------------------------------------------------------
__global__ __launch_bounds__(512, 4) void k_pv(const int* __restrict__ adj,
                                               const uint4* __restrict__ hp4,
                                               const float* __restrict__ EI,
                                               const float* __restrict__ EJ,
                                               const unsigned* __restrict__ emax_u,
                                               float* __restrict__ npart,
                                               float* __restrict__ dpart,
                                               int ntiles) {
  __shared__ __align__(16) uint4 ps4[8 * 64];   // 8 KB P tile (A-fragment layout)
  __shared__ float ejhi[2048], ejlo[2048];      // split's EJ, 0.2*EJ
  __shared__ float A1[64], A2[64], den[64];
  __shared__ unsigned char bml[2][512];         // double-buffered mask bytes
  const int rowbase = blockIdx.x * 64;
  const int split   = blockIdx.y;
  const int jt0     = split * ntiles;
  const int tid     = threadIdx.x;
  const int wid  = tid >> 6, lane = tid & 63;
  const int lo   = lane & 15, hi = lane >> 4;

  float EMAX;
  {
    const unsigned u = *emax_u;
    EMAX = (u & 0x80000000u) ? __uint_as_float(u & 0x7fffffffu) : __uint_as_float(~u);
  }
  if (tid < 64) {
    const float e  = EI[rowbase + tid];
    const float s  = e + EMAX;
    const float mi = fmaxf(s, 0.2f * s);
    A1[tid] = e - mi;
    A2[tid] = 0.2f * e - mi;
    den[tid] = 0.f;
  }
  const bool uselds = (ntiles <= 32);
  if (uselds) {
    int eidx = jt0 * 64 + tid * 4;              // clamp guard (no-op at nsplit=4)
    if (eidx > N_NODES - 4) eidx = N_NODES - 4;
    const float4 ev = *(const float4*)&EJ[eidx];
    *(float4*)&ejhi[tid * 4] = ev;
    float4 el = {0.2f * ev.x, 0.2f * ev.y, 0.2f * ev.z, 0.2f * ev.w};
    *(float4*)&ejlo[tid * 4] = el;
  }

  // ---- adj staging role: thread -> (row = tid>>3, col8 = tid&7) ----
  const int arow = tid >> 3;
  const int* aadj = adj + (size_t)(rowbase + arow) * N_NODES + jt0 * 64 + (tid & 7) * 8;
  // Prologue: pack tile 0 into bml[0]; preload tile 1 into regs.
  {
    const i32x4 v0 = __builtin_nontemporal_load((const i32x4*)(aadj));
    const i32x4 v1 = __builtin_nontemporal_load((const i32x4*)(aadj + 4));
    unsigned by = (v0.x > 0) | ((v0.y > 0) << 1) | ((v0.z > 0) << 2) |
                  ((v0.w > 0) << 3) | ((v1.x > 0) << 4) | ((v1.y > 0) << 5) |
                  ((v1.z > 0) << 6) | ((v1.w > 0) << 7);
    bml[0][tid] = (unsigned char)by;
  }
  i32x4 av0 = {0, 0, 0, 0}, av1 = {0, 0, 0, 0};
  if (ntiles > 1) {
    av0 = __builtin_nontemporal_load((const i32x4*)(aadj + 64));
    av1 = __builtin_nontemporal_load((const i32x4*)(aadj + 68));
  }
  __syncthreads();   // A1/A2, ejhi/ejlo, bml[0] ready

  // P-writer role: slot wid = ksw*4 + msub.
  const int msub = wid & 3, ksw = wid >> 2;
  const int row_p = msub * 16 + lo;
  const int jloc  = ksw * 32 + hi * 8;
  const float a1r = A1[row_p], a2r = A2[row_p];
  const int  mbidx = row_p * 8 + ksw * 4 + hi;   // byte index in bml
  const float* ejg  = EJ + jt0 * 64 + jloc;
  // MFMA-reader role: wave (mg,ng) owns rows [mg*32,+32) x cols [ng*64,+64).
  const int mg = wid >> 2, ng = wid & 3;
  const uint4* hb = hp4 + (ng * 4) * 64 + lane;

  f32x4 acc[2][4] = {};
  float dacc = 0.f;

  for (int jt = 0; jt < ntiles; ++jt) {
    const int tb = (jt0 + jt) * 2048;  // uint4 offset of this tile's first k-block
    // B fragments for this tile (L2/L3-hot).
    const uint4 b00 = hb[tb + 0 * 1024 + 0 * 64];
    const uint4 b01 = hb[tb + 0 * 1024 + 1 * 64];
    const uint4 b02 = hb[tb + 0 * 1024 + 2 * 64];
    const uint4 b03 = hb[tb + 0 * 1024 + 3 * 64];
    const uint4 b10 = hb[tb + 1 * 1024 + 0 * 64];
    const uint4 b11 = hb[tb + 1 * 1024 + 1 * 64];
    const uint4 b12 = hb[tb + 1 * 1024 + 2 * 64];
    const uint4 b13 = hb[tb + 1 * 1024 + 3 * 64];

    // P compute: 8 values/thread; mask byte from bml (written last iter).
    const unsigned mcur = bml[jt & 1][mbidx];
    float eh[8], el[8];
    if (uselds) {
      const float4 h0 = *(const float4*)&ejhi[jt * 64 + jloc];
      const float4 h1 = *(const float4*)&ejhi[jt * 64 + jloc + 4];
      const float4 l0 = *(const float4*)&ejlo[jt * 64 + jloc];
      const float4 l1 = *(const float4*)&ejlo[jt * 64 + jloc + 4];
      eh[0]=h0.x; eh[1]=h0.y; eh[2]=h0.z; eh[3]=h0.w;
      eh[4]=h1.x; eh[5]=h1.y; eh[6]=h1.z; eh[7]=h1.w;
      el[0]=l0.x; el[1]=l0.y; el[2]=l0.z; el[3]=l0.w;
      el[4]=l1.x; el[5]=l1.y; el[6]=l1.z; el[7]=l1.w;
    } else {
      const float4 e0 = *(const float4*)(ejg + jt * 64);
      const float4 e1 = *(const float4*)(ejg + jt * 64 + 4);
      eh[0]=e0.x; eh[1]=e0.y; eh[2]=e0.z; eh[3]=e0.w;
      eh[4]=e1.x; eh[5]=e1.y; eh[6]=e1.z; eh[7]=e1.w;
#pragma unroll
      for (int j = 0; j < 8; ++j) el[j] = 0.2f * eh[j];
    }
    float ph[8];
#pragma unroll
    for (int j = 0; j < 8; ++j) {
      const float s = fmaxf(eh[j] + a1r, el[j] + a2r);
      const float p = __builtin_amdgcn_exp2f(s);
      ph[j] = (mcur & (1u << j)) ? p : 0.f;
    }
    dacc += ((ph[0] + ph[1]) + (ph[2] + ph[3])) + ((ph[4] + ph[5]) + (ph[6] + ph[7]));
    H2U q0, q1, q2, q3;
    q0.h = __builtin_amdgcn_cvt_pkrtz(ph[0], ph[1]);
    q1.h = __builtin_amdgcn_cvt_pkrtz(ph[2], ph[3]);
    q2.h = __builtin_amdgcn_cvt_pkrtz(ph[4], ph[5]);
    q3.h = __builtin_amdgcn_cvt_pkrtz(ph[6], ph[7]);
    uint4 pk = {q0.u, q1.u, q2.u, q3.u};

    asm volatile("" ::: "memory");
    __builtin_amdgcn_s_barrier();        // all waves done reading ps4 (prev tile)
    asm volatile("" ::: "memory");
    ps4[wid * 64 + lane] = pk;
    // Pack mask bytes for tile jt+1 (regs loaded last window); issue coalesced
    // NT loads for tile jt+2 (full tile of latency cover).
    if (jt + 1 < ntiles) {
      unsigned by = (av0.x > 0) | ((av0.y > 0) << 1) | ((av0.z > 0) << 2) |
                    ((av0.w > 0) << 3) | ((av1.x > 0) << 4) | ((av1.y > 0) << 5) |
                    ((av1.z > 0) << 6) | ((av1.w > 0) << 7);
      bml[(jt + 1) & 1][tid] = (unsigned char)by;
      if (jt + 2 < ntiles) {
        av0 = __builtin_nontemporal_load((const i32x4*)(aadj + (jt + 2) * 64));
        av1 = __builtin_nontemporal_load((const i32x4*)(aadj + (jt + 2) * 64 + 4));
      }
    }
    asm volatile("s_waitcnt lgkmcnt(0)" ::: "memory");  // ps4 + bml writes visible
    __builtin_amdgcn_s_barrier();        // P tile ready
    asm volatile("" ::: "memory");

    H8U4 a00, a01, a10, a11;
    a00.u = ps4[(0 * 4 + mg * 2 + 0) * 64 + lane];
    a10.u = ps4[(0 * 4 + mg * 2 + 1) * 64 + lane];
    a01.u = ps4[(1 * 4 + mg * 2 + 0) * 64 + lane];
    a11.u = ps4[(1 * 4 + mg * 2 + 1) * 64 + lane];
    H8U4 b;
    __builtin_amdgcn_s_setprio(1);
    b.u = b00;
    acc[0][0] = __builtin_amdgcn_mfma_f32_16x16x32_f16(a00.h, b.h, acc[0][0], 0, 0, 0);
    acc[1][0] = __builtin_amdgcn_mfma_f32_16x16x32_f16(a10.h, b.h, acc[1][0], 0, 0, 0);
    b.u = b01;
    acc[0][1] = __builtin_amdgcn_mfma_f32_16x16x32_f16(a00.h, b.h, acc[0][1], 0, 0, 0);
    acc[1][1] = __builtin_amdgcn_mfma_f32_16x16x32_f16(a10.h, b.h, acc[1][1], 0, 0, 0);
    b.u = b02;
    acc[0][2] = __builtin_amdgcn_mfma_f32_16x16x32_f16(a00.h, b.h, acc[0][2], 0, 0, 0);
    acc[1][2] = __builtin_amdgcn_mfma_f32_16x16x32_f16(a10.h, b.h, acc[1][2], 0, 0, 0);
    b.u = b03;
    acc[0][3] = __builtin_amdgcn_mfma_f32_16x16x32_f16(a00.h, b.h, acc[0][3], 0, 0, 0);
    acc[1][3] = __builtin_amdgcn_mfma_f32_16x16x32_f16(a10.h, b.h, acc[1][3], 0, 0, 0);
    b.u = b10;
    acc[0][0] = __builtin_amdgcn_mfma_f32_16x16x32_f16(a01.h, b.h, acc[0][0], 0, 0, 0);
    acc[1][0] = __builtin_amdgcn_mfma_f32_16x16x32_f16(a11.h, b.h, acc[1][0], 0, 0, 0);
    b.u = b11;
    acc[0][1] = __builtin_amdgcn_mfma_f32_16x16x32_f16(a01.h, b.h, acc[0][1], 0, 0, 0);
    acc[1][1] = __builtin_amdgcn_mfma_f32_16x16x32_f16(a11.h, b.h, acc[1][1], 0, 0, 0);
    b.u = b12;
    acc[0][2] = __builtin_amdgcn_mfma_f32_16x16x32_f16(a01.h, b.h, acc[0][2], 0, 0, 0);
    acc[1][2] = __builtin_amdgcn_mfma_f32_16x16x32_f16(a11.h, b.h, acc[1][2], 0, 0, 0);
    b.u = b13;
    acc[0][3] = __builtin_amdgcn_mfma_f32_16x16x32_f16(a01.h, b.h, acc[0][3], 0, 0, 0);
    acc[1][3] = __builtin_amdgcn_mfma_f32_16x16x32_f16(a11.h, b.h, acc[1][3], 0, 0, 0);
    __builtin_amdgcn_s_setprio(0);
  }

  atomicAdd(&den[row_p], dacc);
  __syncthreads();

  float* npb = npart + (size_t)split * N_NODES * F_OUT;
#pragma unroll
  for (int mi_ = 0; mi_ < 2; ++mi_) {
    const int rb = rowbase + (mg * 2 + mi_) * 16 + hi * 4;
#pragma unroll
    for (int nf = 0; nf < 4; ++nf) {
      const int col = ng * 64 + nf * 16 + lo;
#pragma unroll
      for (int r2 = 0; r2 < 4; ++r2)
        __builtin_nontemporal_store(acc[mi_][nf][r2],
                                    &npb[(size_t)(rb + r2) * F_OUT + col]);
    }
  }
  if (tid < 64)
    __builtin_nontemporal_store(den[tid],
                                &dpart[(size_t)split * N_NODES + rowbase + tid]);
}

// ---------------------------------------------------------------------------
// k_fin: combine splits, divide by denom, ELU, write output.
// ---------------------------------------------------------------------------
__global__ __launch_bounds__(256) void k_fin(const float* __restrict__ npart,
                                             const float* __restrict__ dpart,
                                             float* __restrict__ out,
                                             int nsplit) {
  const int gid = blockIdx.x * 256 + threadIdx.x;
  const int row = gid >> 6;
  const int c4  = (gid & 63) << 2;
  f32x4 s = {0.f, 0.f, 0.f, 0.f};
  float d = 0.f;
  for (int sp = 0; sp < nsplit; ++sp) {
    const f32x4 v = __builtin_nontemporal_load(
        (const f32x4*)(npart + ((size_t)sp * N_NODES + row) * F_OUT + c4));
    s += v;
    d += dpart[(size_t)sp * N_NODES + row];
  }
  const float inv = 1.f / d;
  float o[4] = {s.x * inv, s.y * inv, s.z * inv, s.w * inv};
#pragma unroll
  for (int i = 0; i < 4; ++i) o[i] = (o[i] > 0.f) ? o[i] : expm1f(o[i]);
  float4 ov = {o[0], o[1], o[2], o[3]};
  *(float4*)(out + (size_t)row * F_OUT + c4) = ov;
}

// ---------------------------------------------------------------------------
extern "C" void kernel_launch(void* const* d_in, const int* in_sizes, int n_in,
                              void* d_out, int out_size, void* d_ws, size_t ws_size,
                              hipStream_t stream) {
  const float* x   = (const float*)d_in[0];
  const int*   adj = (const int*)d_in[1];
  const float* W   = (const float*)d_in[2];
  const float* a   = (const float*)d_in[3];
  float* out = (float*)d_out;
  char*  ws  = (char*)d_ws;

  unsigned short* hpack = (unsigned short*)ws;  // 4 MB, B-fragment layout
  size_t off = (size_t)4 * 1024 * 1024;
  float* EI = (float*)(ws + off); off += (size_t)N_NODES * 4;
  float* EJ = (float*)(ws + off); off += (size_t)N_NODES * 4;
  unsigned* emax_u = (unsigned*)(ws + off); off += 256;
  float* dpart = (float*)(ws + off); off += (size_t)8 * N_NODES * 4;
  unsigned short* wph = (unsigned short*)(ws + off); off += (size_t)F_IN * F_OUT * 2;
  unsigned short* wpl = (unsigned short*)(ws + off); off += (size_t)F_IN * F_OUT * 2;
  float* npart = (float*)(ws + off);

  int nsplit = 4;   // 512 blocks: all co-resident in one dispatch round (r6 lesson)
  while (nsplit > 1 && off + (size_t)nsplit * N_NODES * F_OUT * 4 > ws_size) nsplit >>= 1;

  k_prep<<<dim3((F_IN * F_OUT) / 256), dim3(256), 0, stream>>>(W, wph, wpl, emax_u);
  k_hgemm<<<dim3(N_NODES / 32), dim3(512), 0, stream>>>(
      x, (const uint4*)wph, (const uint4*)wpl, a, hpack, EI, EJ, emax_u);
  k_pv<<<dim3(128, nsplit), dim3(512), 0, stream>>>(adj, (const uint4*)hpack, EI, EJ,
                                                    emax_u, npart, dpart, 128 / nsplit);
  k_fin<<<dim3(N_NODES * 64 / 256), dim3(256), 0, stream>>>(npart, dpart, out, nsplit);
}